// Round 5
// baseline (839.059 us; speedup 1.0000x reference)
//
#include <hip/hip_runtime.h>
#include <hip/hip_bf16.h>
#include <math.h>

#define BATCH 2
#define SEQ   2048
#define EMB   2048
#define NH    16
#define HD    128

typedef __attribute__((ext_vector_type(8))) short short8;
typedef __attribute__((ext_vector_type(4))) float floatx4;

__device__ inline void async_load16(const void* g, void* l) {
    __builtin_amdgcn_global_load_lds(
        (const __attribute__((address_space(1))) unsigned int*)g,
        (__attribute__((address_space(3))) unsigned int*)l, 16, 0, 0);
}

__device__ inline unsigned short bf16_bits(float f) {
    __hip_bfloat16 b = __float2bfloat16(f);
    return *(unsigned short*)&b;
}
__device__ inline void split_bf16(float f, unsigned short& h, unsigned short& l) {
    __hip_bfloat16 hb = __float2bfloat16(f);
    h = *(unsigned short*)&hb;
    float r = f - __bfloat162float(hb);
    __hip_bfloat16 lb = __float2bfloat16(r);
    l = *(unsigned short*)&lb;
}

// ======================= plain bf16 MFMA GEMM (m97 structure) =======================
#define GT 128
#define GK 32

__global__ __launch_bounds__(256) void gemm_bf16(
    const unsigned short* __restrict__ A,
    const unsigned short* __restrict__ Bt,
    float* __restrict__ C, int M, int N, int K)
{
    __shared__ unsigned short As[GT * GK];
    __shared__ unsigned short Bs[GT * GK];

    const int tid  = threadIdx.x;
    const int w    = tid >> 6;
    const int lane = tid & 63;
    const int wr   = w >> 1, wc = w & 1;
    const int row0 = blockIdx.y * GT;
    const int col0 = blockIdx.x * GT;

    floatx4 acc[4][4];
    #pragma unroll
    for (int i = 0; i < 4; i++)
        #pragma unroll
        for (int j = 0; j < 4; j++)
            acc[i][j] = (floatx4){0.f, 0.f, 0.f, 0.f};

    const int srow  = lane >> 2;
    const int skoff = (lane & 3) * 8;
    const int fm = lane & 15;
    const int fk = (lane >> 4) * 8;

    for (int k0 = 0; k0 < K; k0 += GK) {
        #pragma unroll
        for (int t = 0; t < 2; t++) {
            const int c = w * 2 + t;
            async_load16(A  + (size_t)(row0 + c * 16 + srow) * K + k0 + skoff, (char*)As + c * 1024);
            async_load16(Bt + (size_t)(col0 + c * 16 + srow) * K + k0 + skoff, (char*)Bs + c * 1024);
        }
        __syncthreads();

        short8 af[4], bf[4];
        #pragma unroll
        for (int i = 0; i < 4; i++) {
            af[i] = *(const short8*)&As[(wr * 64 + i * 16 + fm) * GK + fk];
            bf[i] = *(const short8*)&Bs[(wc * 64 + i * 16 + fm) * GK + fk];
        }
        #pragma unroll
        for (int i = 0; i < 4; i++)
            #pragma unroll
            for (int j = 0; j < 4; j++)
                acc[i][j] = __builtin_amdgcn_mfma_f32_16x16x32_bf16(af[i], bf[j], acc[i][j], 0, 0, 0);
        __syncthreads();
    }

    const int quad = lane >> 4;
    #pragma unroll
    for (int i = 0; i < 4; i++)
        #pragma unroll
        for (int j = 0; j < 4; j++) {
            const size_t base = (size_t)(row0 + wr * 64 + i * 16 + quad * 4) * N
                              + col0 + wc * 64 + j * 16 + fm;
            #pragma unroll
            for (int r = 0; r < 4; r++)
                C[base + (size_t)r * N] = acc[i][j][r];
        }
}

// ======================= split (hi/lo) bf16 MFMA GEMM =======================
__global__ __launch_bounds__(256) void gemm_bf16_split(
    const unsigned short* __restrict__ Ah, const unsigned short* __restrict__ Al,
    const unsigned short* __restrict__ Bh, const unsigned short* __restrict__ Bl,
    float* __restrict__ C, int M, int N, int K)
{
    __shared__ unsigned short AsH[GT * GK], AsL[GT * GK];
    __shared__ unsigned short BsH[GT * GK], BsL[GT * GK];

    const int tid  = threadIdx.x;
    const int w    = tid >> 6;
    const int lane = tid & 63;
    const int wr   = w >> 1, wc = w & 1;
    const int row0 = blockIdx.y * GT;
    const int col0 = blockIdx.x * GT;

    floatx4 acc[4][4];
    #pragma unroll
    for (int i = 0; i < 4; i++)
        #pragma unroll
        for (int j = 0; j < 4; j++)
            acc[i][j] = (floatx4){0.f, 0.f, 0.f, 0.f};

    const int srow  = lane >> 2;
    const int skoff = (lane & 3) * 8;
    const int fm = lane & 15;
    const int fk = (lane >> 4) * 8;

    for (int k0 = 0; k0 < K; k0 += GK) {
        #pragma unroll
        for (int t = 0; t < 2; t++) {
            const int c = w * 2 + t;
            const size_t ao = (size_t)(row0 + c * 16 + srow) * K + k0 + skoff;
            const size_t bo = (size_t)(col0 + c * 16 + srow) * K + k0 + skoff;
            async_load16(Ah + ao, (char*)AsH + c * 1024);
            async_load16(Al + ao, (char*)AsL + c * 1024);
            async_load16(Bh + bo, (char*)BsH + c * 1024);
            async_load16(Bl + bo, (char*)BsL + c * 1024);
        }
        __syncthreads();

        short8 afh[4], afl[4], bfh[4], bfl[4];
        #pragma unroll
        for (int i = 0; i < 4; i++) {
            const int arow = (wr * 64 + i * 16 + fm) * GK + fk;
            const int brow = (wc * 64 + i * 16 + fm) * GK + fk;
            afh[i] = *(const short8*)&AsH[arow];
            afl[i] = *(const short8*)&AsL[arow];
            bfh[i] = *(const short8*)&BsH[brow];
            bfl[i] = *(const short8*)&BsL[brow];
        }
        #pragma unroll
        for (int i = 0; i < 4; i++)
            #pragma unroll
            for (int j = 0; j < 4; j++) {
                acc[i][j] = __builtin_amdgcn_mfma_f32_16x16x32_bf16(afh[i], bfh[j], acc[i][j], 0, 0, 0);
                acc[i][j] = __builtin_amdgcn_mfma_f32_16x16x32_bf16(afh[i], bfl[j], acc[i][j], 0, 0, 0);
                acc[i][j] = __builtin_amdgcn_mfma_f32_16x16x32_bf16(afl[i], bfh[j], acc[i][j], 0, 0, 0);
            }
        __syncthreads();
    }

    const int quad = lane >> 4;
    #pragma unroll
    for (int i = 0; i < 4; i++)
        #pragma unroll
        for (int j = 0; j < 4; j++) {
            const size_t base = (size_t)(row0 + wr * 64 + i * 16 + quad * 4) * N
                              + col0 + wc * 64 + j * 16 + fm;
            #pragma unroll
            for (int r = 0; r < 4; r++)
                C[base + (size_t)r * N] = acc[i][j][r];
        }
}

// ======================= casts / weight prep =======================
__global__ __launch_bounds__(256) void cast_split_f32(
    const float* __restrict__ in, unsigned short* __restrict__ hi,
    unsigned short* __restrict__ lo, int n)
{
    int i = (blockIdx.x * 256 + threadIdx.x) * 4;
    if (i >= n) return;
    float4 v = *(const float4*)&in[i];
    ushort4 h, l;
    split_bf16(v.x, h.x, l.x);
    split_bf16(v.y, h.y, l.y);
    split_bf16(v.z, h.z, l.z);
    split_bf16(v.w, h.w, l.w);
    *(ushort4*)&hi[i] = h;
    *(ushort4*)&lo[i] = l;
}

__global__ __launch_bounds__(256) void transpose_cast(
    const float* __restrict__ W, unsigned short* __restrict__ Wt, int K, int N)
{
    __shared__ float tile[32][33];
    const int k0 = blockIdx.y * 32, n0 = blockIdx.x * 32;
    const int tx = threadIdx.x, ty = threadIdx.y;
    #pragma unroll
    for (int i = 0; i < 4; i++)
        tile[ty + i * 8][tx] = W[(size_t)(k0 + ty + i * 8) * N + n0 + tx];
    __syncthreads();
    #pragma unroll
    for (int i = 0; i < 4; i++)
        Wt[(size_t)(n0 + ty + i * 8) * K + k0 + tx] = bf16_bits(tile[tx][ty + i * 8]);
}

__global__ __launch_bounds__(256) void transpose_cast_split(
    const float* __restrict__ W, unsigned short* __restrict__ WtH,
    unsigned short* __restrict__ WtL, int K, int N)
{
    __shared__ float tile[32][33];
    const int k0 = blockIdx.y * 32, n0 = blockIdx.x * 32;
    const int tx = threadIdx.x, ty = threadIdx.y;
    #pragma unroll
    for (int i = 0; i < 4; i++)
        tile[ty + i * 8][tx] = W[(size_t)(k0 + ty + i * 8) * N + n0 + tx];
    __syncthreads();
    #pragma unroll
    for (int i = 0; i < 4; i++) {
        unsigned short h, l;
        split_bf16(tile[tx][ty + i * 8], h, l);
        size_t idx = (size_t)(n0 + ty + i * 8) * K + k0 + tx;
        WtH[idx] = h;
        WtL[idx] = l;
    }
}

// ======================= prep_qk: rmsnorm + split + head-major relayout =======================
__global__ __launch_bounds__(256) void prep_qk(
    const float* __restrict__ in, const float* __restrict__ scale,
    unsigned short* __restrict__ hi, unsigned short* __restrict__ lo, int swz)
{
    __shared__ float ws4[4];
    const int r = blockIdx.x * 2 + (threadIdx.x >> 7);
    const int d = threadIdx.x & 127;
    const int b = r >> 15;
    const int s = (r >> 4) & 2047;
    const int h = r & 15;
    const float v = in[(size_t)r * 128 + d];
    float ss = v * v;
    #pragma unroll
    for (int off = 1; off < 64; off <<= 1) ss += __shfl_xor(ss, off, 64);
    if ((threadIdx.x & 63) == 0) ws4[threadIdx.x >> 6] = ss;
    __syncthreads();
    const int g = (threadIdx.x >> 7) << 1;
    const float inv = rsqrtf((ws4[g] + ws4[g + 1]) * (1.0f / HD) + 1e-6f);
    const float val = v * inv * scale[d];
    unsigned short hb, lb;
    split_bf16(val, hb, lb);
    const int dd = swz ? (((((d >> 3) ^ (s & 15))) << 3) | (d & 7)) : d;
    const size_t o = ((size_t)(b * NH + h) * SEQ + s) * 128 + dd;
    hi[o] = hb;
    lo[o] = lb;
}

// ======================= prep_v =======================
__global__ __launch_bounds__(256) void prep_v(
    const float* __restrict__ v, unsigned short* __restrict__ Vt)
{
    __shared__ unsigned short T[128][72];
    const int bh = blockIdx.y, ktile = blockIdx.x;
    const int b = bh >> 4, h = bh & 15;
    const int key = threadIdx.x >> 2, dg = threadIdx.x & 3;
    const size_t vrow = ((size_t)(b * SEQ + ktile * 64 + key) * NH + h) * 128;
    #pragma unroll
    for (int i2 = 0; i2 < 8; i2++) {
        const int d0 = dg * 4 + i2 * 16;
        float4 x = *(const float4*)&v[vrow + d0];
        T[d0 + 0][key] = bf16_bits(x.x);
        T[d0 + 1][key] = bf16_bits(x.y);
        T[d0 + 2][key] = bf16_bits(x.z);
        T[d0 + 3][key] = bf16_bits(x.w);
    }
    __syncthreads();
    const int d = threadIdx.x >> 1, half = threadIdx.x & 1;
    const size_t obase = ((size_t)bh * 32 + ktile) * 8192 + (size_t)d * 64;
    #pragma unroll
    for (int cc = 0; cc < 4; cc++) {
        const int cs = half * 4 + cc;
        const int kb = (cs ^ (d & 7)) << 3;
        short8 val = *(const short8*)&T[d][kb];
        *(short8*)&Vt[obase + cs * 8] = val;
    }
}

// ======================= MFMA flash attention v3: double-buffered, 1 barrier/tile =======================
// grid (SEQ/128, BATCH*NH), 256 threads = 4 waves; wave w owns q-rows w*32..+31.
// LDS 112 KB -> 1 block/CU; prefetch of tile t+1 overlaps full compute of tile t.
#define ATQ 128
#define ATK 64

__global__ __launch_bounds__(256, 1) void attn3(
    const unsigned short* __restrict__ Qh, const unsigned short* __restrict__ Ql,
    const unsigned short* __restrict__ Kh, const unsigned short* __restrict__ Kl,
    const unsigned short* __restrict__ Vt, __hip_bfloat16* __restrict__ AO)
{
    __shared__ unsigned short KsH[2][ATK * 128];   // 32 KB  [key][d'] (chunk ^= key&15)
    __shared__ unsigned short KsL[2][ATK * 128];   // 32 KB
    __shared__ unsigned short Vts[2][HD * 64];     // 32 KB  [d][key'] (chunk ^= d&7)
    __shared__ unsigned short Ps[ATQ * 64];        // 16 KB  P[row][key'] (chunk ^= row&7)

    const int tid  = threadIdx.x;
    const int w    = tid >> 6;
    const int lane = tid & 63;
    const int quad = lane >> 4;
    const int fm   = lane & 15;
    const int bh = blockIdx.y;
    const int b = bh >> 4, h = bh & 15;
    const int q0 = blockIdx.x * ATQ;

    const size_t hbase = (size_t)(b * NH + h) * SEQ;

    // ---- Q fragments (pre-split bf16) ----
    short8 qh[2][4], ql[2][4];
    #pragma unroll
    for (int i = 0; i < 2; i++) {
        const size_t row = hbase + q0 + w * 32 + i * 16 + fm;
        #pragma unroll
        for (int kc = 0; kc < 4; kc++) {
            const size_t off = row * 128 + kc * 32 + quad * 8;
            qh[i][kc] = *(const short8*)&Qh[off];
            ql[i][kc] = *(const short8*)&Ql[off];
        }
    }

    floatx4 oacc[2][8];
    #pragma unroll
    for (int i = 0; i < 2; i++)
        #pragma unroll
        for (int df = 0; df < 8; df++)
            oacc[i][df] = (floatx4){0.f, 0.f, 0.f, 0.f};
    float m_[2][4], l_[2][4];
    #pragma unroll
    for (int i = 0; i < 2; i++)
        #pragma unroll
        for (int r = 0; r < 4; r++) { m_[i][r] = -1e30f; l_[i][r] = 0.f; }

    const unsigned short* gkh0 = Kh + hbase * 128;
    const unsigned short* gkl0 = Kl + hbase * 128;
    const unsigned short* gvt0 = Vt + (size_t)bh * 32 * 8192;

    // ---- prologue: stage tile 0 into buffer 0 ----
    #pragma unroll
    for (int c = 0; c < 4; c++) {
        const int ch = w * 4 + c;
        const size_t go = (size_t)ch * 512 + lane * 8;
        async_load16(gkh0 + go, (char*)KsH[0] + ch * 1024);
        async_load16(gkl0 + go, (char*)KsL[0] + ch * 1024);
        async_load16(gvt0 + go, (char*)Vts[0] + ch * 1024);
    }
    __syncthreads();   // drain: tile 0 staged

    for (int ktile = 0; ktile < SEQ / ATK; ktile++) {
        const int cur = ktile & 1;

        // ---- prefetch tile t+1 into the other buffer (drained at end-of-body barrier) ----
        if (ktile + 1 < SEQ / ATK) {
            const unsigned short* gkh = gkh0 + (size_t)(ktile + 1) * ATK * 128;
            const unsigned short* gkl = gkl0 + (size_t)(ktile + 1) * ATK * 128;
            const unsigned short* gvt = gvt0 + (size_t)(ktile + 1) * 8192;
            #pragma unroll
            for (int c = 0; c < 4; c++) {
                const int ch = w * 4 + c;
                const size_t go = (size_t)ch * 512 + lane * 8;
                async_load16(gkh + go, (char*)KsH[1 - cur] + ch * 1024);
                async_load16(gkl + go, (char*)KsL[1 - cur] + ch * 1024);
                async_load16(gvt + go, (char*)Vts[1 - cur] + ch * 1024);
            }
        }

        // ---- S = Q K^T (3-term hi/lo) from buffer cur ----
        floatx4 sacc[2][4];
        #pragma unroll
        for (int i = 0; i < 2; i++)
            #pragma unroll
            for (int jf = 0; jf < 4; jf++)
                sacc[i][jf] = (floatx4){0.f, 0.f, 0.f, 0.f};
        #pragma unroll
        for (int kc = 0; kc < 4; kc++)
            #pragma unroll
            for (int jf = 0; jf < 4; jf++) {
                const int koff = (jf * 16 + fm) * 128 + (((kc * 4 + quad) ^ fm) << 3);
                short8 kh8 = *(const short8*)&KsH[cur][koff];
                short8 kl8 = *(const short8*)&KsL[cur][koff];
                #pragma unroll
                for (int i = 0; i < 2; i++) {
                    sacc[i][jf] = __builtin_amdgcn_mfma_f32_16x16x32_bf16(qh[i][kc], kh8, sacc[i][jf], 0, 0, 0);
                    sacc[i][jf] = __builtin_amdgcn_mfma_f32_16x16x32_bf16(qh[i][kc], kl8, sacc[i][jf], 0, 0, 0);
                    sacc[i][jf] = __builtin_amdgcn_mfma_f32_16x16x32_bf16(ql[i][kc], kh8, sacc[i][jf], 0, 0, 0);
                }
            }

        // ---- online softmax (registers) ----
        float alpha_[2][4];
        #pragma unroll
        for (int i = 0; i < 2; i++)
            #pragma unroll
            for (int r = 0; r < 4; r++) {
                float mx = fmaxf(fmaxf(sacc[i][0][r], sacc[i][1][r]),
                                 fmaxf(sacc[i][2][r], sacc[i][3][r]));
                mx = fmaxf(mx, __shfl_xor(mx, 1));
                mx = fmaxf(mx, __shfl_xor(mx, 2));
                mx = fmaxf(mx, __shfl_xor(mx, 4));
                mx = fmaxf(mx, __shfl_xor(mx, 8));
                const float mold = m_[i][r];
                const float mnew = fmaxf(mold, mx);
                const float al = __expf(mold - mnew);
                m_[i][r] = mnew;
                alpha_[i][r] = al;
                float rs = 0.f;
                #pragma unroll
                for (int jf = 0; jf < 4; jf++) {
                    float p = __expf(sacc[i][jf][r] - mnew);
                    sacc[i][jf][r] = p;
                    rs += p;
                }
                rs += __shfl_xor(rs, 1);
                rs += __shfl_xor(rs, 2);
                rs += __shfl_xor(rs, 4);
                rs += __shfl_xor(rs, 8);
                l_[i][r] = l_[i][r] * al + rs;
            }
        #pragma unroll
        for (int i = 0; i < 2; i++)
            #pragma unroll
            for (int df = 0; df < 8; df++)
                #pragma unroll
                for (int r = 0; r < 4; r++)
                    oacc[i][df][r] *= alpha_[i][r];

        // ---- P -> bf16 into dedicated Ps (own rows only; wave-local ordering) ----
        #pragma unroll
        for (int i = 0; i < 2; i++)
            #pragma unroll
            for (int jf = 0; jf < 4; jf++)
                #pragma unroll
                for (int r = 0; r < 4; r++) {
                    const int row = w * 32 + i * 16 + quad * 4 + r;
                    const int chunk = jf * 2 + (fm >> 3);
                    const int colp = ((chunk ^ (row & 7)) << 3) | (fm & 7);
                    Ps[row * 64 + colp] = bf16_bits(sacc[i][jf][r]);
                }

        // ---- O += P V from buffer cur ----
        #pragma unroll
        for (int kc2 = 0; kc2 < 2; kc2++) {
            short8 ap[2];
            #pragma unroll
            for (int i = 0; i < 2; i++) {
                const int row = w * 32 + i * 16 + fm;
                ap[i] = *(const short8*)&Ps[row * 64 + (((kc2 * 4 + quad) ^ (row & 7)) << 3)];
            }
            #pragma unroll
            for (int df = 0; df < 8; df++) {
                const int d = df * 16 + fm;
                short8 bv = *(const short8*)&Vts[cur][d * 64 + (((kc2 * 4 + quad) ^ (d & 7)) << 3)];
                #pragma unroll
                for (int i = 0; i < 2; i++)
                    oacc[i][df] = __builtin_amdgcn_mfma_f32_16x16x32_bf16(ap[i], bv, oacc[i][df], 0, 0, 0);
            }
        }

        // single barrier: drains prefetch (t+1 ready) + protects buffer swap
        __syncthreads();
    }

    // ---- epilogue: AO bf16 [b,s,h,d] ----
    const size_t obase = ((size_t)b * SEQ * NH + h) * HD;
    const size_t rstr = (size_t)NH * HD;
    float linv[2][4];
    #pragma unroll
    for (int i = 0; i < 2; i++)
        #pragma unroll
        for (int r = 0; r < 4; r++) linv[i][r] = 1.0f / l_[i][r];
    #pragma unroll
    for (int i = 0; i < 2; i++)
        #pragma unroll
        for (int df = 0; df < 8; df++)
            #pragma unroll
            for (int r = 0; r < 4; r++) {
                const int row = q0 + w * 32 + i * 16 + quad * 4 + r;
                const int d = df * 16 + fm;
                AO[obase + (size_t)row * rstr + d] = __float2bfloat16(oacc[i][df][r] * linv[i][r]);
            }
}

// ======================= launch =======================
extern "C" void kernel_launch(void* const* d_in, const int* in_sizes, int n_in,
                              void* d_out, int out_size, void* d_ws, size_t ws_size,
                              hipStream_t stream) {
    const float* x  = (const float*)d_in[0];
    const float* wq = (const float*)d_in[1];
    const float* wk = (const float*)d_in[2];
    const float* wv = (const float*)d_in[3];
    const float* wo = (const float*)d_in[4];
    const float* q_scale = (const float*)d_in[5];
    const float* k_scale = (const float*)d_in[6];
    float* out = (float*)d_out;

    const size_t T = (size_t)BATCH * SEQ * NH * HD;   // 8388608
    const size_t W = (size_t)EMB * NH * HD;           // 4194304

    float* q = (float*)d_ws;                          // fp32 [b,s,h,d]
    float* k = q + T;
    float* v = k + T;
    unsigned short* xh   = (unsigned short*)(v + T);  // reused as Qh after GEMMs
    unsigned short* xl   = xh + T;                    // reused as Ql
    unsigned short* aob  = xl + T;
    unsigned short* Kh   = aob + T;
    unsigned short* Kl   = Kh + T;
    unsigned short* Vtb  = Kl + T;
    unsigned short* wqTh = Vtb + T;
    unsigned short* wqTl = wqTh + W;
    unsigned short* wkTh = wqTl + W;
    unsigned short* wkTl = wkTh + W;
    unsigned short* wvT  = wkTl + W;
    unsigned short* woT  = wvT + W;

    const int M = BATCH * SEQ;   // 4096
    const int N = NH * HD;       // 2048
    const int K = EMB;           // 2048

    cast_split_f32<<<(int)(T / 4 + 255) / 256, 256, 0, stream>>>(x, xh, xl, (int)T);
    dim3 tblk(32, 8);
    transpose_cast_split<<<dim3(N / 32, K / 32), tblk, 0, stream>>>(wq, wqTh, wqTl, K, N);
    transpose_cast_split<<<dim3(N / 32, K / 32), tblk, 0, stream>>>(wk, wkTh, wkTl, K, N);
    transpose_cast<<<dim3(N / 32, K / 32), tblk, 0, stream>>>(wv, wvT, K, N);
    transpose_cast<<<dim3(EMB / 32, (NH * HD) / 32), tblk, 0, stream>>>(wo, woT, NH * HD, EMB);

    dim3 ggrid(N / GT, M / GT);
    gemm_bf16_split<<<ggrid, 256, 0, stream>>>(xh, xl, wqTh, wqTl, q, M, N, K);
    gemm_bf16_split<<<ggrid, 256, 0, stream>>>(xh, xl, wkTh, wkTl, k, M, N, K);
    gemm_bf16<<<ggrid, 256, 0, stream>>>(xh, wvT, v, M, N, K);

    unsigned short* Qh = xh;
    unsigned short* Ql = xl;
    prep_qk<<<(int)(T / 128 / 2), 256, 0, stream>>>(q, q_scale, Qh, Ql, 0);
    prep_qk<<<(int)(T / 128 / 2), 256, 0, stream>>>(k, k_scale, Kh, Kl, 1);
    prep_v<<<dim3(SEQ / ATK, BATCH * NH), 256, 0, stream>>>(v, Vtb);

    attn3<<<dim3(SEQ / ATQ, BATCH * NH), 256, 0, stream>>>(Qh, Ql, Kh, Kl, Vtb, (__hip_bfloat16*)aob);

    gemm_bf16<<<dim3(EMB / GT, M / GT), 256, 0, stream>>>(aob, woT, out, M, EMB, NH * HD);
}

// Round 6
// 756.625 us; speedup vs baseline: 1.1089x; 1.1089x over previous
//
#include <hip/hip_runtime.h>
#include <hip/hip_bf16.h>
#include <math.h>

#define BATCH 2
#define SEQ   2048
#define EMB   2048
#define NH    16
#define HD    128

typedef __attribute__((ext_vector_type(8))) short short8;
typedef __attribute__((ext_vector_type(4))) float floatx4;

__device__ inline void async_load16(const void* g, void* l) {
    __builtin_amdgcn_global_load_lds(
        (const __attribute__((address_space(1))) unsigned int*)g,
        (__attribute__((address_space(3))) unsigned int*)l, 16, 0, 0);
}

__device__ inline unsigned short bf16_bits(float f) {
    __hip_bfloat16 b = __float2bfloat16(f);
    return *(unsigned short*)&b;
}
__device__ inline void split_bf16(float f, unsigned short& h, unsigned short& l) {
    __hip_bfloat16 hb = __float2bfloat16(f);
    h = *(unsigned short*)&hb;
    float r = f - __bfloat162float(hb);
    __hip_bfloat16 lb = __float2bfloat16(r);
    l = *(unsigned short*)&lb;
}

// ======================= plain bf16 MFMA GEMM (m97 structure) =======================
#define GT 128
#define GK 32

__global__ __launch_bounds__(256) void gemm_bf16(
    const unsigned short* __restrict__ A,
    const unsigned short* __restrict__ Bt,
    float* __restrict__ C, int M, int N, int K)
{
    __shared__ unsigned short As[GT * GK];
    __shared__ unsigned short Bs[GT * GK];

    const int tid  = threadIdx.x;
    const int w    = tid >> 6;
    const int lane = tid & 63;
    const int wr   = w >> 1, wc = w & 1;
    const int row0 = blockIdx.y * GT;
    const int col0 = blockIdx.x * GT;

    floatx4 acc[4][4];
    #pragma unroll
    for (int i = 0; i < 4; i++)
        #pragma unroll
        for (int j = 0; j < 4; j++)
            acc[i][j] = (floatx4){0.f, 0.f, 0.f, 0.f};

    const int srow  = lane >> 2;
    const int skoff = (lane & 3) * 8;
    const int fm = lane & 15;
    const int fk = (lane >> 4) * 8;

    for (int k0 = 0; k0 < K; k0 += GK) {
        #pragma unroll
        for (int t = 0; t < 2; t++) {
            const int c = w * 2 + t;
            async_load16(A  + (size_t)(row0 + c * 16 + srow) * K + k0 + skoff, (char*)As + c * 1024);
            async_load16(Bt + (size_t)(col0 + c * 16 + srow) * K + k0 + skoff, (char*)Bs + c * 1024);
        }
        __syncthreads();

        short8 af[4], bf[4];
        #pragma unroll
        for (int i = 0; i < 4; i++) {
            af[i] = *(const short8*)&As[(wr * 64 + i * 16 + fm) * GK + fk];
            bf[i] = *(const short8*)&Bs[(wc * 64 + i * 16 + fm) * GK + fk];
        }
        #pragma unroll
        for (int i = 0; i < 4; i++)
            #pragma unroll
            for (int j = 0; j < 4; j++)
                acc[i][j] = __builtin_amdgcn_mfma_f32_16x16x32_bf16(af[i], bf[j], acc[i][j], 0, 0, 0);
        __syncthreads();
    }

    const int quad = lane >> 4;
    #pragma unroll
    for (int i = 0; i < 4; i++)
        #pragma unroll
        for (int j = 0; j < 4; j++) {
            const size_t base = (size_t)(row0 + wr * 64 + i * 16 + quad * 4) * N
                              + col0 + wc * 64 + j * 16 + fm;
            #pragma unroll
            for (int r = 0; r < 4; r++)
                C[base + (size_t)r * N] = acc[i][j][r];
        }
}

// ======================= split (hi/lo) bf16 MFMA GEMM =======================
__global__ __launch_bounds__(256) void gemm_bf16_split(
    const unsigned short* __restrict__ Ah, const unsigned short* __restrict__ Al,
    const unsigned short* __restrict__ Bh, const unsigned short* __restrict__ Bl,
    float* __restrict__ C, int M, int N, int K)
{
    __shared__ unsigned short AsH[GT * GK], AsL[GT * GK];
    __shared__ unsigned short BsH[GT * GK], BsL[GT * GK];

    const int tid  = threadIdx.x;
    const int w    = tid >> 6;
    const int lane = tid & 63;
    const int wr   = w >> 1, wc = w & 1;
    const int row0 = blockIdx.y * GT;
    const int col0 = blockIdx.x * GT;

    floatx4 acc[4][4];
    #pragma unroll
    for (int i = 0; i < 4; i++)
        #pragma unroll
        for (int j = 0; j < 4; j++)
            acc[i][j] = (floatx4){0.f, 0.f, 0.f, 0.f};

    const int srow  = lane >> 2;
    const int skoff = (lane & 3) * 8;
    const int fm = lane & 15;
    const int fk = (lane >> 4) * 8;

    for (int k0 = 0; k0 < K; k0 += GK) {
        #pragma unroll
        for (int t = 0; t < 2; t++) {
            const int c = w * 2 + t;
            const size_t ao = (size_t)(row0 + c * 16 + srow) * K + k0 + skoff;
            const size_t bo = (size_t)(col0 + c * 16 + srow) * K + k0 + skoff;
            async_load16(Ah + ao, (char*)AsH + c * 1024);
            async_load16(Al + ao, (char*)AsL + c * 1024);
            async_load16(Bh + bo, (char*)BsH + c * 1024);
            async_load16(Bl + bo, (char*)BsL + c * 1024);
        }
        __syncthreads();

        short8 afh[4], afl[4], bfh[4], bfl[4];
        #pragma unroll
        for (int i = 0; i < 4; i++) {
            const int arow = (wr * 64 + i * 16 + fm) * GK + fk;
            const int brow = (wc * 64 + i * 16 + fm) * GK + fk;
            afh[i] = *(const short8*)&AsH[arow];
            afl[i] = *(const short8*)&AsL[arow];
            bfh[i] = *(const short8*)&BsH[brow];
            bfl[i] = *(const short8*)&BsL[brow];
        }
        #pragma unroll
        for (int i = 0; i < 4; i++)
            #pragma unroll
            for (int j = 0; j < 4; j++) {
                acc[i][j] = __builtin_amdgcn_mfma_f32_16x16x32_bf16(afh[i], bfh[j], acc[i][j], 0, 0, 0);
                acc[i][j] = __builtin_amdgcn_mfma_f32_16x16x32_bf16(afh[i], bfl[j], acc[i][j], 0, 0, 0);
                acc[i][j] = __builtin_amdgcn_mfma_f32_16x16x32_bf16(afl[i], bfh[j], acc[i][j], 0, 0, 0);
            }
        __syncthreads();
    }

    const int quad = lane >> 4;
    #pragma unroll
    for (int i = 0; i < 4; i++)
        #pragma unroll
        for (int j = 0; j < 4; j++) {
            const size_t base = (size_t)(row0 + wr * 64 + i * 16 + quad * 4) * N
                              + col0 + wc * 64 + j * 16 + fm;
            #pragma unroll
            for (int r = 0; r < 4; r++)
                C[base + (size_t)r * N] = acc[i][j][r];
        }
}

// ======================= casts / weight prep =======================
__global__ __launch_bounds__(256) void cast_split_f32(
    const float* __restrict__ in, unsigned short* __restrict__ hi,
    unsigned short* __restrict__ lo, int n)
{
    int i = (blockIdx.x * 256 + threadIdx.x) * 4;
    if (i >= n) return;
    float4 v = *(const float4*)&in[i];
    ushort4 h, l;
    split_bf16(v.x, h.x, l.x);
    split_bf16(v.y, h.y, l.y);
    split_bf16(v.z, h.z, l.z);
    split_bf16(v.w, h.w, l.w);
    *(ushort4*)&hi[i] = h;
    *(ushort4*)&lo[i] = l;
}

__global__ __launch_bounds__(256) void transpose_cast(
    const float* __restrict__ W, unsigned short* __restrict__ Wt, int K, int N)
{
    __shared__ float tile[32][33];
    const int k0 = blockIdx.y * 32, n0 = blockIdx.x * 32;
    const int tx = threadIdx.x, ty = threadIdx.y;
    #pragma unroll
    for (int i = 0; i < 4; i++)
        tile[ty + i * 8][tx] = W[(size_t)(k0 + ty + i * 8) * N + n0 + tx];
    __syncthreads();
    #pragma unroll
    for (int i = 0; i < 4; i++)
        Wt[(size_t)(n0 + ty + i * 8) * K + k0 + tx] = bf16_bits(tile[tx][ty + i * 8]);
}

__global__ __launch_bounds__(256) void transpose_cast_split(
    const float* __restrict__ W, unsigned short* __restrict__ WtH,
    unsigned short* __restrict__ WtL, int K, int N)
{
    __shared__ float tile[32][33];
    const int k0 = blockIdx.y * 32, n0 = blockIdx.x * 32;
    const int tx = threadIdx.x, ty = threadIdx.y;
    #pragma unroll
    for (int i = 0; i < 4; i++)
        tile[ty + i * 8][tx] = W[(size_t)(k0 + ty + i * 8) * N + n0 + tx];
    __syncthreads();
    #pragma unroll
    for (int i = 0; i < 4; i++) {
        unsigned short h, l;
        split_bf16(tile[tx][ty + i * 8], h, l);
        size_t idx = (size_t)(n0 + ty + i * 8) * K + k0 + tx;
        WtH[idx] = h;
        WtL[idx] = l;
    }
}

// ======================= prep_qk: rmsnorm + split + head-major relayout =======================
__global__ __launch_bounds__(256) void prep_qk(
    const float* __restrict__ in, const float* __restrict__ scale,
    unsigned short* __restrict__ hi, unsigned short* __restrict__ lo, int swz)
{
    __shared__ float ws4[4];
    const int r = blockIdx.x * 2 + (threadIdx.x >> 7);
    const int d = threadIdx.x & 127;
    const int b = r >> 15;
    const int s = (r >> 4) & 2047;
    const int h = r & 15;
    const float v = in[(size_t)r * 128 + d];
    float ss = v * v;
    #pragma unroll
    for (int off = 1; off < 64; off <<= 1) ss += __shfl_xor(ss, off, 64);
    if ((threadIdx.x & 63) == 0) ws4[threadIdx.x >> 6] = ss;
    __syncthreads();
    const int g = (threadIdx.x >> 7) << 1;
    const float inv = rsqrtf((ws4[g] + ws4[g + 1]) * (1.0f / HD) + 1e-6f);
    const float val = v * inv * scale[d];
    unsigned short hb, lb;
    split_bf16(val, hb, lb);
    const int dd = swz ? (((((d >> 3) ^ (s & 15))) << 3) | (d & 7)) : d;
    const size_t o = ((size_t)(b * NH + h) * SEQ + s) * 128 + dd;
    hi[o] = hb;
    lo[o] = lb;
}

// ======================= prep_v =======================
__global__ __launch_bounds__(256) void prep_v(
    const float* __restrict__ v, unsigned short* __restrict__ Vt)
{
    __shared__ unsigned short T[128][72];
    const int bh = blockIdx.y, ktile = blockIdx.x;
    const int b = bh >> 4, h = bh & 15;
    const int key = threadIdx.x >> 2, dg = threadIdx.x & 3;
    const size_t vrow = ((size_t)(b * SEQ + ktile * 64 + key) * NH + h) * 128;
    #pragma unroll
    for (int i2 = 0; i2 < 8; i2++) {
        const int d0 = dg * 4 + i2 * 16;
        float4 x = *(const float4*)&v[vrow + d0];
        T[d0 + 0][key] = bf16_bits(x.x);
        T[d0 + 1][key] = bf16_bits(x.y);
        T[d0 + 2][key] = bf16_bits(x.z);
        T[d0 + 3][key] = bf16_bits(x.w);
    }
    __syncthreads();
    const int d = threadIdx.x >> 1, half = threadIdx.x & 1;
    const size_t obase = ((size_t)bh * 32 + ktile) * 8192 + (size_t)d * 64;
    #pragma unroll
    for (int cc = 0; cc < 4; cc++) {
        const int cs = half * 4 + cc;
        const int kb = (cs ^ (d & 7)) << 3;
        short8 val = *(const short8*)&T[d][kb];
        *(short8*)&Vt[obase + cs * 8] = val;
    }
}

// ======================= MFMA flash attention v4 =======================
// 512 threads = 8 waves (2/SIMD for latency hiding), ATQ=256 (32 q-rows/wave),
// double-buffered KV staging, ONE barrier per tile. Grid (8, 32) = 256 blocks = 1/CU.
// LDS 128 KB -> 1 block/CU (intended).
#define ATQ 256
#define ATK 64

__global__ __launch_bounds__(512, 1) void attn4(
    const unsigned short* __restrict__ Qh, const unsigned short* __restrict__ Ql,
    const unsigned short* __restrict__ Kh, const unsigned short* __restrict__ Kl,
    const unsigned short* __restrict__ Vt, __hip_bfloat16* __restrict__ AO)
{
    __shared__ unsigned short KsH[2][ATK * 128];   // 32 KB  [key][d'] (chunk ^= key&15)
    __shared__ unsigned short KsL[2][ATK * 128];   // 32 KB
    __shared__ unsigned short Vts[2][HD * 64];     // 32 KB  [d][key'] (chunk ^= d&7)
    __shared__ unsigned short Ps[ATQ * 64];        // 32 KB  P[row][key'] (chunk ^= row&7)

    const int tid  = threadIdx.x;
    const int w    = tid >> 6;        // 0..7
    const int lane = tid & 63;
    const int quad = lane >> 4;
    const int fm   = lane & 15;
    const int bh = blockIdx.y;
    const int b = bh >> 4, h = bh & 15;
    const int q0 = blockIdx.x * ATQ;

    const size_t hbase = (size_t)(b * NH + h) * SEQ;

    // ---- Q fragments (pre-split bf16); wave owns rows w*32..w*32+31 ----
    short8 qh[2][4], ql[2][4];
    #pragma unroll
    for (int i = 0; i < 2; i++) {
        const size_t row = hbase + q0 + w * 32 + i * 16 + fm;
        #pragma unroll
        for (int kc = 0; kc < 4; kc++) {
            const size_t off = row * 128 + kc * 32 + quad * 8;
            qh[i][kc] = *(const short8*)&Qh[off];
            ql[i][kc] = *(const short8*)&Ql[off];
        }
    }

    floatx4 oacc[2][8];
    #pragma unroll
    for (int i = 0; i < 2; i++)
        #pragma unroll
        for (int df = 0; df < 8; df++)
            oacc[i][df] = (floatx4){0.f, 0.f, 0.f, 0.f};
    float m_[2][4], l_[2][4];
    #pragma unroll
    for (int i = 0; i < 2; i++)
        #pragma unroll
        for (int r = 0; r < 4; r++) { m_[i][r] = -1e30f; l_[i][r] = 0.f; }

    const unsigned short* gkh0 = Kh + hbase * 128;
    const unsigned short* gkl0 = Kl + hbase * 128;
    const unsigned short* gvt0 = Vt + (size_t)bh * 32 * 8192;

    // staging: 48 chunks of 1 KB (KsH 16, KsL 16, Vts 16); wave w -> chunks w*6..w*6+5
    const int ch0 = w * 6;

    // ---- prologue: stage tile 0 into buffer 0 ----
    #pragma unroll
    for (int c = 0; c < 6; c++) {
        const int ch = ch0 + c;
        const size_t go = (size_t)(ch & 15) * 512 + lane * 8;
        if (ch < 16)      async_load16(gkh0 + go, (char*)KsH[0] + ch * 1024);
        else if (ch < 32) async_load16(gkl0 + go, (char*)KsL[0] + (ch - 16) * 1024);
        else              async_load16(gvt0 + go, (char*)Vts[0] + (ch - 32) * 1024);
    }
    __syncthreads();   // drain: tile 0 staged

    for (int ktile = 0; ktile < SEQ / ATK; ktile++) {
        const int cur = ktile & 1;

        // ---- prefetch tile t+1 into other buffer (drained by end-of-tile barrier) ----
        if (ktile + 1 < SEQ / ATK) {
            const unsigned short* gkh = gkh0 + (size_t)(ktile + 1) * ATK * 128;
            const unsigned short* gkl = gkl0 + (size_t)(ktile + 1) * ATK * 128;
            const unsigned short* gvt = gvt0 + (size_t)(ktile + 1) * 8192;
            #pragma unroll
            for (int c = 0; c < 6; c++) {
                const int ch = ch0 + c;
                const size_t go = (size_t)(ch & 15) * 512 + lane * 8;
                if (ch < 16)      async_load16(gkh + go, (char*)KsH[1 - cur] + ch * 1024);
                else if (ch < 32) async_load16(gkl + go, (char*)KsL[1 - cur] + (ch - 16) * 1024);
                else              async_load16(gvt + go, (char*)Vts[1 - cur] + (ch - 32) * 1024);
            }
        }

        // ---- S = Q K^T (3-term hi/lo) from buffer cur ----
        floatx4 sacc[2][4];
        #pragma unroll
        for (int i = 0; i < 2; i++)
            #pragma unroll
            for (int jf = 0; jf < 4; jf++)
                sacc[i][jf] = (floatx4){0.f, 0.f, 0.f, 0.f};
        #pragma unroll
        for (int kc = 0; kc < 4; kc++)
            #pragma unroll
            for (int jf = 0; jf < 4; jf++) {
                const int koff = (jf * 16 + fm) * 128 + (((kc * 4 + quad) ^ fm) << 3);
                short8 kh8 = *(const short8*)&KsH[cur][koff];
                short8 kl8 = *(const short8*)&KsL[cur][koff];
                #pragma unroll
                for (int i = 0; i < 2; i++) {
                    sacc[i][jf] = __builtin_amdgcn_mfma_f32_16x16x32_bf16(qh[i][kc], kh8, sacc[i][jf], 0, 0, 0);
                    sacc[i][jf] = __builtin_amdgcn_mfma_f32_16x16x32_bf16(qh[i][kc], kl8, sacc[i][jf], 0, 0, 0);
                    sacc[i][jf] = __builtin_amdgcn_mfma_f32_16x16x32_bf16(ql[i][kc], kh8, sacc[i][jf], 0, 0, 0);
                }
            }

        // ---- online softmax (registers) ----
        float alpha_[2][4];
        #pragma unroll
        for (int i = 0; i < 2; i++)
            #pragma unroll
            for (int r = 0; r < 4; r++) {
                float mx = fmaxf(fmaxf(sacc[i][0][r], sacc[i][1][r]),
                                 fmaxf(sacc[i][2][r], sacc[i][3][r]));
                mx = fmaxf(mx, __shfl_xor(mx, 1));
                mx = fmaxf(mx, __shfl_xor(mx, 2));
                mx = fmaxf(mx, __shfl_xor(mx, 4));
                mx = fmaxf(mx, __shfl_xor(mx, 8));
                const float mold = m_[i][r];
                const float mnew = fmaxf(mold, mx);
                const float al = __expf(mold - mnew);
                m_[i][r] = mnew;
                alpha_[i][r] = al;
                float rs = 0.f;
                #pragma unroll
                for (int jf = 0; jf < 4; jf++) {
                    float p = __expf(sacc[i][jf][r] - mnew);
                    sacc[i][jf][r] = p;
                    rs += p;
                }
                rs += __shfl_xor(rs, 1);
                rs += __shfl_xor(rs, 2);
                rs += __shfl_xor(rs, 4);
                rs += __shfl_xor(rs, 8);
                l_[i][r] = l_[i][r] * al + rs;
            }
        #pragma unroll
        for (int i = 0; i < 2; i++)
            #pragma unroll
            for (int df = 0; df < 8; df++)
                #pragma unroll
                for (int r = 0; r < 4; r++)
                    oacc[i][df][r] *= alpha_[i][r];

        // ---- P -> bf16 into Ps (own rows; wave-local ordering, no barrier) ----
        #pragma unroll
        for (int i = 0; i < 2; i++)
            #pragma unroll
            for (int jf = 0; jf < 4; jf++)
                #pragma unroll
                for (int r = 0; r < 4; r++) {
                    const int row = w * 32 + i * 16 + quad * 4 + r;
                    const int chunk = jf * 2 + (fm >> 3);
                    const int colp = ((chunk ^ (row & 7)) << 3) | (fm & 7);
                    Ps[row * 64 + colp] = bf16_bits(sacc[i][jf][r]);
                }

        // ---- O += P V from buffer cur ----
        #pragma unroll
        for (int kc2 = 0; kc2 < 2; kc2++) {
            short8 ap[2];
            #pragma unroll
            for (int i = 0; i < 2; i++) {
                const int row = w * 32 + i * 16 + fm;
                ap[i] = *(const short8*)&Ps[row * 64 + (((kc2 * 4 + quad) ^ (row & 7)) << 3)];
            }
            #pragma unroll
            for (int df = 0; df < 8; df++) {
                const int d = df * 16 + fm;
                short8 bv = *(const short8*)&Vts[cur][d * 64 + (((kc2 * 4 + quad) ^ (d & 7)) << 3)];
                #pragma unroll
                for (int i = 0; i < 2; i++)
                    oacc[i][df] = __builtin_amdgcn_mfma_f32_16x16x32_bf16(ap[i], bv, oacc[i][df], 0, 0, 0);
            }
        }

        // single barrier per tile: drains prefetch + protects buffer swap
        __syncthreads();
    }

    // ---- epilogue: AO bf16 [b,s,h,d] ----
    const size_t obase = ((size_t)b * SEQ * NH + h) * HD;
    const size_t rstr = (size_t)NH * HD;
    float linv[2][4];
    #pragma unroll
    for (int i = 0; i < 2; i++)
        #pragma unroll
        for (int r = 0; r < 4; r++) linv[i][r] = 1.0f / l_[i][r];
    #pragma unroll
    for (int i = 0; i < 2; i++)
        #pragma unroll
        for (int df = 0; df < 8; df++)
            #pragma unroll
            for (int r = 0; r < 4; r++) {
                const int row = q0 + w * 32 + i * 16 + quad * 4 + r;
                const int d = df * 16 + fm;
                AO[obase + (size_t)row * rstr + d] = __float2bfloat16(oacc[i][df][r] * linv[i][r]);
            }
}

// ======================= launch =======================
extern "C" void kernel_launch(void* const* d_in, const int* in_sizes, int n_in,
                              void* d_out, int out_size, void* d_ws, size_t ws_size,
                              hipStream_t stream) {
    const float* x  = (const float*)d_in[0];
    const float* wq = (const float*)d_in[1];
    const float* wk = (const float*)d_in[2];
    const float* wv = (const float*)d_in[3];
    const float* wo = (const float*)d_in[4];
    const float* q_scale = (const float*)d_in[5];
    const float* k_scale = (const float*)d_in[6];
    float* out = (float*)d_out;

    const size_t T = (size_t)BATCH * SEQ * NH * HD;   // 8388608
    const size_t W = (size_t)EMB * NH * HD;           // 4194304

    float* q = (float*)d_ws;                          // fp32 [b,s,h,d]
    float* k = q + T;
    float* v = k + T;
    unsigned short* xh   = (unsigned short*)(v + T);  // reused as Qh after GEMMs
    unsigned short* xl   = xh + T;                    // reused as Ql
    unsigned short* aob  = xl + T;
    unsigned short* Kh   = aob + T;
    unsigned short* Kl   = Kh + T;
    unsigned short* Vtb  = Kl + T;
    unsigned short* wqTh = Vtb + T;
    unsigned short* wqTl = wqTh + W;
    unsigned short* wkTh = wqTl + W;
    unsigned short* wkTl = wkTh + W;
    unsigned short* wvT  = wkTl + W;
    unsigned short* woT  = wvT + W;

    const int M = BATCH * SEQ;   // 4096
    const int N = NH * HD;       // 2048
    const int K = EMB;           // 2048

    cast_split_f32<<<(int)(T / 4 + 255) / 256, 256, 0, stream>>>(x, xh, xl, (int)T);
    dim3 tblk(32, 8);
    transpose_cast_split<<<dim3(N / 32, K / 32), tblk, 0, stream>>>(wq, wqTh, wqTl, K, N);
    transpose_cast_split<<<dim3(N / 32, K / 32), tblk, 0, stream>>>(wk, wkTh, wkTl, K, N);
    transpose_cast<<<dim3(N / 32, K / 32), tblk, 0, stream>>>(wv, wvT, K, N);
    transpose_cast<<<dim3(EMB / 32, (NH * HD) / 32), tblk, 0, stream>>>(wo, woT, NH * HD, EMB);

    dim3 ggrid(N / GT, M / GT);
    gemm_bf16_split<<<ggrid, 256, 0, stream>>>(xh, xl, wqTh, wqTl, q, M, N, K);
    gemm_bf16_split<<<ggrid, 256, 0, stream>>>(xh, xl, wkTh, wkTl, k, M, N, K);
    gemm_bf16<<<ggrid, 256, 0, stream>>>(xh, wvT, v, M, N, K);

    unsigned short* Qh = xh;
    unsigned short* Ql = xl;
    prep_qk<<<(int)(T / 128 / 2), 256, 0, stream>>>(q, q_scale, Qh, Ql, 0);
    prep_qk<<<(int)(T / 128 / 2), 256, 0, stream>>>(k, k_scale, Kh, Kl, 1);
    prep_v<<<dim3(SEQ / ATK, BATCH * NH), 256, 0, stream>>>(v, Vtb);

    attn4<<<dim3(SEQ / ATQ, BATCH * NH), 512, 0, stream>>>(Qh, Ql, Kh, Kl, Vtb, (__hip_bfloat16*)aob);

    gemm_bf16<<<dim3(EMB / GT, M / GT), 256, 0, stream>>>(aob, woT, out, M, EMB, NH * HD);
}